// Round 3
// baseline (609.391 us; speedup 1.0000x reference)
//
#include <hip/hip_runtime.h>

typedef unsigned short u16;
typedef unsigned int   u32;
typedef __attribute__((ext_vector_type(4))) float f32x4;
typedef __attribute__((ext_vector_type(4))) int   i32x4;

#define NPAIR 32768   // B*H
#define NB    25
#define FD    128

__device__ __forceinline__ float bflo(u32 u){ return __uint_as_float(u << 16); }
__device__ __forceinline__ float bfhi(u32 u){ return __uint_as_float(u & 0xFFFF0000u); }
__device__ __forceinline__ u16 f2bf(float f){
  u32 u = __float_as_uint(f);
  u += 0x7FFFu + ((u >> 16) & 1u);   // RNE
  return (u16)(u >> 16);
}
__device__ __forceinline__ float rowsum16(float x){
  x += __shfl_xor(x, 1);
  x += __shfl_xor(x, 2);
  x += __shfl_xor(x, 4);
  x += __shfl_xor(x, 8);
  return x;
}

// wave-local dtype sniff on the first 128 u16 of a buffer known to hold ~N(0,1)-scale data.
// fp32 data: low halves have random bits -> bf16-exponent >= 141 appears w.p. ~1 per few samples.
// fp32 storage of bf16-rounded values: even u16 (low half) == 0.
__device__ __forceinline__ bool sniff_fp32(const u16* __restrict__ buf, int lane){
  const u16 v1 = buf[lane], v2 = buf[64 + lane];
  int e1 = (v1 >> 7) & 0xFF, e2 = (v2 >> 7) & 0xFF;
  int e = e1 > e2 ? e1 : e2;
  #pragma unroll
  for(int m=1; m<=32; m<<=1){ int o = __shfl_xor(e, m); e = e > o ? e : o; }
  unsigned long long zb = __ballot(((lane & 1) == 0) && (v1 == 0 || v2 == 0));
  return (e >= 141) || (__popcll(zb) >= 20);
}

// ---------------- Kernel B (fused): per-block wa = [W@a_self | W@a_neigh] in LDS,
// then one wave per (b,h) pair: logits -> leaky_relu -> softmax -> weighted x-sum -> xbar (bf16)
template<bool FP32>
__device__ __forceinline__ void attn_body(const void* __restrict__ xs_, const void* __restrict__ xn_,
                                          const void* __restrict__ w_, const void* __restrict__ as_,
                                          const void* __restrict__ an_,
                                          float* __restrict__ wa_s, float* __restrict__ wa_n,
                                          u16* __restrict__ xbar,
                                          const int p, const int tid, const int lane){
  // ---- stage 1: wa into LDS. thread t: row f = t>>1, d-half h = t&1.
  {
    const int f = tid >> 1, h = tid & 1;
    float pS = 0.f, pN = 0.f;
    if (FP32){
      const float* wrow = (const float*)w_  + f*FD + 64*h;
      const float* ap   = (const float*)as_ + 64*h;
      const float* np   = (const float*)an_ + 64*h;
      #pragma unroll
      for(int k=0;k<16;++k){
        float4 wv = *(const float4*)(wrow + 4*k);
        float4 av = *(const float4*)(ap   + 4*k);
        float4 nv = *(const float4*)(np   + 4*k);
        pS += wv.x*av.x + wv.y*av.y + wv.z*av.z + wv.w*av.w;
        pN += wv.x*nv.x + wv.y*nv.y + wv.z*nv.z + wv.w*nv.w;
      }
    } else {
      const u16* wrow = (const u16*)w_  + f*FD + 64*h;
      const u16* ap   = (const u16*)as_ + 64*h;
      const u16* np   = (const u16*)an_ + 64*h;
      #pragma unroll
      for(int k=0;k<8;++k){
        uint4 wv = *(const uint4*)(wrow + 8*k);
        uint4 av = *(const uint4*)(ap   + 8*k);
        uint4 nv = *(const uint4*)(np   + 8*k);
        pS += bflo(wv.x)*bflo(av.x) + bfhi(wv.x)*bfhi(av.x);
        pS += bflo(wv.y)*bflo(av.y) + bfhi(wv.y)*bfhi(av.y);
        pS += bflo(wv.z)*bflo(av.z) + bfhi(wv.z)*bfhi(av.z);
        pS += bflo(wv.w)*bflo(av.w) + bfhi(wv.w)*bfhi(av.w);
        pN += bflo(wv.x)*bflo(nv.x) + bfhi(wv.x)*bfhi(nv.x);
        pN += bflo(wv.y)*bflo(nv.y) + bfhi(wv.y)*bfhi(nv.y);
        pN += bflo(wv.z)*bflo(nv.z) + bfhi(wv.z)*bfhi(nv.z);
        pN += bflo(wv.w)*bflo(nv.w) + bfhi(wv.w)*bfhi(nv.w);
      }
    }
    pS += __shfl_xor(pS, 1);
    pN += __shfl_xor(pN, 1);
    if (h == 0){ wa_s[f] = pS; wa_n[f] = pN; }
  }
  __syncthreads();

  // ---- stage 2: one wave per pair
  const int g  = lane >> 4;      // vector v = 4*i + g
  const int q  = lane & 15;      // feature lane: f = 8q..8q+7
  const int f0 = q << 3;

  float was[8], wan[8];
  {
    float4 a = *(const float4*)(wa_s + f0);
    float4 b = *(const float4*)(wa_s + f0 + 4);
    was[0]=a.x; was[1]=a.y; was[2]=a.z; was[3]=a.w;
    was[4]=b.x; was[5]=b.y; was[6]=b.z; was[7]=b.w;
    float4 c = *(const float4*)(wa_n + f0);
    float4 d = *(const float4*)(wa_n + f0 + 4);
    wan[0]=c.x; wan[1]=c.y; wan[2]=c.z; wan[3]=c.w;
    wan[4]=d.x; wan[5]=d.y; wan[6]=d.z; wan[7]=d.w;
  }

  float xf[7][8];
  #pragma unroll
  for(int i=0;i<7;++i){
    const int v = 4*i + g;
    if (v <= NB){
      if (FP32){
        const float* src = (v==0) ? ((const float*)xs_ + (size_t)p*FD + f0)
                                  : ((const float*)xn_ + (size_t)p*(NB*FD) + (size_t)(v-1)*FD + f0);
        float4 A = *(const float4*)src;
        float4 B = *(const float4*)(src + 4);
        xf[i][0]=A.x; xf[i][1]=A.y; xf[i][2]=A.z; xf[i][3]=A.w;
        xf[i][4]=B.x; xf[i][5]=B.y; xf[i][6]=B.z; xf[i][7]=B.w;
      } else {
        const u16* src = (v==0) ? ((const u16*)xs_ + (size_t)p*FD + f0)
                                : ((const u16*)xn_ + (size_t)p*(NB*FD) + (size_t)(v-1)*FD + f0);
        uint4 d = *(const uint4*)src;
        xf[i][0]=bflo(d.x); xf[i][1]=bfhi(d.x);
        xf[i][2]=bflo(d.y); xf[i][3]=bfhi(d.y);
        xf[i][4]=bflo(d.z); xf[i][5]=bfhi(d.z);
        xf[i][6]=bflo(d.w); xf[i][7]=bfhi(d.w);
      }
    } else {
      #pragma unroll
      for(int j=0;j<8;++j) xf[i][j] = 0.f;
    }
  }

  float pn[7];
  #pragma unroll
  for(int i=0;i<7;++i){
    float s = 0.f;
    #pragma unroll
    for(int j=0;j<8;++j) s += xf[i][j]*wan[j];
    pn[i] = rowsum16(s);
  }
  float ps = 0.f;
  #pragma unroll
  for(int j=0;j<8;++j) ps += xf[0][j]*was[j];
  ps = rowsum16(ps);
  const float s_self = __shfl(ps, 0);   // vector 0 lives on row 0

  float u[7];
  #pragma unroll
  for(int i=0;i<7;++i){
    const int v = 4*i + g;
    if (v <= NB){
      float t = s_self + pn[i];
      u[i] = fmaxf(t, 0.2f*t);          // leaky_relu(0.2)
    } else u[i] = -3.0e38f;
  }
  float m = u[0];
  #pragma unroll
  for(int i=1;i<7;++i) m = fmaxf(m, u[i]);
  m = fmaxf(m, __shfl_xor(m, 16));
  m = fmaxf(m, __shfl_xor(m, 32));

  float e[7]; float S = 0.f;
  #pragma unroll
  for(int i=0;i<7;++i){
    const int v = 4*i + g;
    e[i] = (v <= NB) ? __expf(u[i] - m) : 0.f;
    S += e[i];
  }
  S += __shfl_xor(S, 16);
  S += __shfl_xor(S, 32);
  const float rinv = 1.0f / S;

  float acc[8];
  #pragma unroll
  for(int j=0;j<8;++j) acc[j] = 0.f;
  #pragma unroll
  for(int i=0;i<7;++i)
    #pragma unroll
    for(int j=0;j<8;++j) acc[j] += e[i]*xf[i][j];
  #pragma unroll
  for(int j=0;j<8;++j){
    acc[j] += __shfl_xor(acc[j], 16);
    acc[j] += __shfl_xor(acc[j], 32);
    acc[j] *= rinv;
  }
  if (g == 0){
    u32 o0 = (u32)f2bf(acc[0]) | ((u32)f2bf(acc[1])<<16);
    u32 o1 = (u32)f2bf(acc[2]) | ((u32)f2bf(acc[3])<<16);
    u32 o2 = (u32)f2bf(acc[4]) | ((u32)f2bf(acc[5])<<16);
    u32 o3 = (u32)f2bf(acc[6]) | ((u32)f2bf(acc[7])<<16);
    *(uint4*)(xbar + (size_t)p*FD + f0) = make_uint4(o0,o1,o2,o3);
  }
}

__global__ __launch_bounds__(256) void attn_xbar(const void* __restrict__ xs, const void* __restrict__ xn,
                                                 const void* __restrict__ w, const void* __restrict__ as,
                                                 const void* __restrict__ an,
                                                 u16* __restrict__ xbar){
  __shared__ float wa_s[FD], wa_n[FD];
  const int tid  = threadIdx.x;
  const int lane = tid & 63;
  const int p    = blockIdx.x*4 + (tid >> 6);
  const bool isf32 = sniff_fp32((const u16*)xs, lane);
  if (isf32) attn_body<true >(xs, xn, w, as, an, wa_s, wa_n, xbar, p, tid, lane);
  else       attn_body<false>(xs, xn, w, as, an, wa_s, wa_n, xbar, p, tid, lane);
}

// ---------------- Kernel C: out = relu(xbar @ W), MFMA via inline asm
__global__ __launch_bounds__(256) void matvec_out(const u16* __restrict__ xbar,
                                                  const void* __restrict__ w_,
                                                  void* __restrict__ out_,
                                                  const u16* __restrict__ xsniff){
  __shared__ u16 wlds[FD*FD];
  const int tid = threadIdx.x;
  const bool isf32 = sniff_fp32(xsniff, tid & 63);
  if (isf32){
    const float* w = (const float*)w_;
    #pragma unroll
    for(int i=0;i<8;++i){
      const int e = (i*256 + tid)*8;
      float4 A = *(const float4*)(w + e);
      float4 B = *(const float4*)(w + e + 4);
      u32 o0 = (u32)f2bf(A.x) | ((u32)f2bf(A.y)<<16);
      u32 o1 = (u32)f2bf(A.z) | ((u32)f2bf(A.w)<<16);
      u32 o2 = (u32)f2bf(B.x) | ((u32)f2bf(B.y)<<16);
      u32 o3 = (u32)f2bf(B.z) | ((u32)f2bf(B.w)<<16);
      *(uint4*)(wlds + e) = make_uint4(o0,o1,o2,o3);
    }
  } else {
    const u16* w = (const u16*)w_;
    #pragma unroll
    for(int i=0;i<8;++i){
      const int e = (i*256 + tid)*8;
      *(uint4*)(wlds + e) = *(const uint4*)(w + e);
    }
  }
  __syncthreads();

  const int lane = tid & 63, wv = tid >> 6;
  const int col  = lane & 15, quad = lane >> 4;

  // B fragments: B[k = kt*32 + quad*8 + j][n = nt*16 + col]
  i32x4 bfru[8][4];
  #pragma unroll
  for(int nt=0;nt<8;++nt)
    #pragma unroll
    for(int kt=0;kt<4;++kt){
      union { u16 s[8]; i32x4 u; } bb;
      #pragma unroll
      for(int j=0;j<8;++j) bb.s[j] = wlds[(kt*32 + quad*8 + j)*FD + nt*16 + col];
      bfru[nt][kt] = bb.u;
    }

  const int waveG = blockIdx.x*4 + wv;   // 1024 waves
  #pragma unroll
  for(int s=0;s<2;++s){
    const int tile = waveG + s*1024;     // 2048 tiles of 16 rows
    const u16* arow = xbar + (size_t)(tile*16 + col)*FD;
    f32x4 acc[8];
    #pragma unroll
    for(int nt=0;nt<8;++nt){ f32x4 z = {0.f,0.f,0.f,0.f}; acc[nt] = z; }
    #pragma unroll
    for(int kt=0;kt<4;++kt){
      i32x4 av = *(const i32x4*)(arow + kt*32 + quad*8);   // A[m=col][k=kt*32+quad*8+j]
      #pragma unroll
      for(int nt=0;nt<8;++nt){
        asm volatile("s_nop 1\n\t"
                     "v_mfma_f32_16x16x32_bf16 %0, %1, %2, %0\n\t"
                     "s_nop 7\n\t"
                     "s_nop 7"
                     : "+v"(acc[nt]) : "v"(av), "v"(bfru[nt][kt]));
      }
    }
    if (isf32){
      float* orow = (float*)out_ + (size_t)tile*(16*FD);
      #pragma unroll
      for(int nt=0;nt<8;++nt)
        #pragma unroll
        for(int r=0;r<4;++r)
          orow[(quad*4+r)*FD + nt*16 + col] = fmaxf(acc[nt][r], 0.f);
    } else {
      u16* orow = (u16*)out_ + (size_t)tile*(16*FD);
      #pragma unroll
      for(int nt=0;nt<8;++nt)
        #pragma unroll
        for(int r=0;r<4;++r)
          orow[(quad*4+r)*FD + nt*16 + col] = f2bf(fmaxf(acc[nt][r], 0.f));
    }
  }
}

extern "C" void kernel_launch(void* const* d_in, const int* in_sizes, int n_in,
                              void* d_out, int out_size, void* d_ws, size_t ws_size,
                              hipStream_t stream){
  const void* x_self  = d_in[0];
  const void* x_neigh = d_in[1];
  const void* w_feat  = d_in[2];
  const void* a_self  = d_in[3];
  const void* a_neigh = d_in[4];

  u16* xbar = (u16*)d_ws;   // [32768][128] bf16 = 8 MB

  attn_xbar <<<NPAIR/4, 256, 0, stream>>>(x_self, x_neigh, w_feat, a_self, a_neigh, xbar);
  matvec_out<<<256,     256, 0, stream>>>(xbar, w_feat, d_out, (const u16*)x_self);
}

// Round 4
// 565.217 us; speedup vs baseline: 1.0782x; 1.0782x over previous
//
#include <hip/hip_runtime.h>

typedef unsigned short u16;
typedef unsigned int   u32;
typedef __attribute__((ext_vector_type(4))) float f32x4;
typedef __attribute__((ext_vector_type(4))) int   i32x4;

#define NPAIR 32768   // B*H
#define NB    25
#define FD    128

__device__ __forceinline__ float bflo(u32 u){ return __uint_as_float(u << 16); }
__device__ __forceinline__ float bfhi(u32 u){ return __uint_as_float(u & 0xFFFF0000u); }
__device__ __forceinline__ u16 f2bf(float f){
  u32 u = __float_as_uint(f);
  u += 0x7FFFu + ((u >> 16) & 1u);   // RNE
  return (u16)(u >> 16);
}
// sum across each 16-lane row (masks 1..8 stay within the row)
__device__ __forceinline__ float rowsum16(float x){
  x += __shfl_xor(x, 1);
  x += __shfl_xor(x, 2);
  x += __shfl_xor(x, 4);
  x += __shfl_xor(x, 8);
  return x;
}

// ---------------- Kernel A: dtype sniff + wa = [W@a_self | W@a_neigh] (fp32 in ws)
__global__ __launch_bounds__(64) void prep_wa(const void* w_, const void* as_, const void* an_,
                                              const u16* __restrict__ xsniff,
                                              float* __restrict__ wa, int* __restrict__ flag_out){
  const int l = threadIdx.x;
  // --- sniff x_self[0:128] as u16: fp32 data has random-exponent garbage in low halves
  const u16 v1 = xsniff[l], v2 = xsniff[64 + l];
  int e1 = (v1 >> 7) & 0xFF, e2 = (v2 >> 7) & 0xFF;
  int e = e1 > e2 ? e1 : e2;
  #pragma unroll
  for(int m=1; m<=32; m<<=1){ int o = __shfl_xor(e, m); e = e > o ? e : o; }
  // fp32 storage of bf16-rounded values: even-indexed u16s (low halves) are exactly 0
  unsigned long long zb = __ballot(((l & 1) == 0) && (v1 == 0 || v2 == 0));
  const bool isf32 = (e >= 141) || (__popcll(zb) >= 20);

  const int f = blockIdx.x;
  float ps, pn;
  if (isf32){
    const float* w  = (const float*)w_;
    const float* as = (const float*)as_;
    const float* an = (const float*)an_;
    float w0 = w[f*FD + 2*l], w1 = w[f*FD + 2*l + 1];
    ps = w0*as[2*l] + w1*as[2*l+1];
    pn = w0*an[2*l] + w1*an[2*l+1];
  } else {
    const u16* w  = (const u16*)w_;
    const u16* as = (const u16*)as_;
    const u16* an = (const u16*)an_;
    u32 wd = *(const u32*)(w + f*FD + 2*l);
    u32 av = *(const u32*)(as + 2*l);
    u32 nv = *(const u32*)(an + 2*l);
    ps = bflo(wd)*bflo(av) + bfhi(wd)*bfhi(av);
    pn = bflo(wd)*bflo(nv) + bfhi(wd)*bfhi(nv);
  }
  #pragma unroll
  for(int m=1; m<=32; m<<=1){ ps += __shfl_xor(ps, m); pn += __shfl_xor(pn, m); }
  if (l == 0){ wa[f] = ps; wa[FD + f] = pn; }
  if (blockIdx.x == 0 && l == 0) flag_out[0] = isf32 ? 1 : 0;
}

// ---------------- Kernel B body: one wave per (b,h) pair; xbar = softmax-weighted x (bf16)
template<bool FP32>
__device__ __forceinline__ void attn_body(const void* __restrict__ xs_, const void* __restrict__ xn_,
                                          const float* __restrict__ wa, u16* __restrict__ xbar,
                                          const int p, const int lane){
  const int g  = lane >> 4;      // row-group: vector v = 4*i + g
  const int q  = lane & 15;      // feature lane: f = 8q..8q+7
  const int f0 = q << 3;

  float was[8], wan[8];
  {
    float4 a = *(const float4*)(wa + f0);
    float4 b = *(const float4*)(wa + f0 + 4);
    was[0]=a.x; was[1]=a.y; was[2]=a.z; was[3]=a.w;
    was[4]=b.x; was[5]=b.y; was[6]=b.z; was[7]=b.w;
    float4 c = *(const float4*)(wa + FD + f0);
    float4 d = *(const float4*)(wa + FD + f0 + 4);
    wan[0]=c.x; wan[1]=c.y; wan[2]=c.z; wan[3]=c.w;
    wan[4]=d.x; wan[5]=d.y; wan[6]=d.z; wan[7]=d.w;
  }

  float xf[7][8];
  #pragma unroll
  for(int i=0;i<7;++i){
    const int v = 4*i + g;
    if (v <= NB){
      if (FP32){
        const float* src = (v==0) ? ((const float*)xs_ + (size_t)p*FD + f0)
                                  : ((const float*)xn_ + (size_t)p*(NB*FD) + (size_t)(v-1)*FD + f0);
        float4 A = *(const float4*)src;
        float4 B = *(const float4*)(src + 4);
        xf[i][0]=A.x; xf[i][1]=A.y; xf[i][2]=A.z; xf[i][3]=A.w;
        xf[i][4]=B.x; xf[i][5]=B.y; xf[i][6]=B.z; xf[i][7]=B.w;
      } else {
        const u16* src = (v==0) ? ((const u16*)xs_ + (size_t)p*FD + f0)
                                : ((const u16*)xn_ + (size_t)p*(NB*FD) + (size_t)(v-1)*FD + f0);
        uint4 d = *(const uint4*)src;
        xf[i][0]=bflo(d.x); xf[i][1]=bfhi(d.x);
        xf[i][2]=bflo(d.y); xf[i][3]=bfhi(d.y);
        xf[i][4]=bflo(d.z); xf[i][5]=bfhi(d.z);
        xf[i][6]=bflo(d.w); xf[i][7]=bfhi(d.w);
      }
    } else {
      #pragma unroll
      for(int j=0;j<8;++j) xf[i][j] = 0.f;
    }
  }

  float pn[7];
  #pragma unroll
  for(int i=0;i<7;++i){
    float s = 0.f;
    #pragma unroll
    for(int j=0;j<8;++j) s += xf[i][j]*wan[j];
    pn[i] = rowsum16(s);
  }
  float ps = 0.f;
  #pragma unroll
  for(int j=0;j<8;++j) ps += xf[0][j]*was[j];
  ps = rowsum16(ps);
  const float s_self = __shfl(ps, 0);   // row 0 holds x_self . wa_self

  float u[7];
  #pragma unroll
  for(int i=0;i<7;++i){
    const int v = 4*i + g;
    if (v <= NB){
      float t = s_self + pn[i];
      u[i] = fmaxf(t, 0.2f*t);          // leaky_relu(0.2)
    } else u[i] = -3.0e38f;
  }
  float m = u[0];
  #pragma unroll
  for(int i=1;i<7;++i) m = fmaxf(m, u[i]);
  m = fmaxf(m, __shfl_xor(m, 16));
  m = fmaxf(m, __shfl_xor(m, 32));

  float e[7]; float S = 0.f;
  #pragma unroll
  for(int i=0;i<7;++i){
    const int v = 4*i + g;
    e[i] = (v <= NB) ? __expf(u[i] - m) : 0.f;
    S += e[i];
  }
  S += __shfl_xor(S, 16);
  S += __shfl_xor(S, 32);
  const float rinv = 1.0f / S;

  float acc[8];
  #pragma unroll
  for(int j=0;j<8;++j) acc[j] = 0.f;
  #pragma unroll
  for(int i=0;i<7;++i)
    #pragma unroll
    for(int j=0;j<8;++j) acc[j] += e[i]*xf[i][j];
  #pragma unroll
  for(int j=0;j<8;++j){
    acc[j] += __shfl_xor(acc[j], 16);
    acc[j] += __shfl_xor(acc[j], 32);
    acc[j] *= rinv;
  }
  if (g == 0){
    u32 o0 = (u32)f2bf(acc[0]) | ((u32)f2bf(acc[1])<<16);
    u32 o1 = (u32)f2bf(acc[2]) | ((u32)f2bf(acc[3])<<16);
    u32 o2 = (u32)f2bf(acc[4]) | ((u32)f2bf(acc[5])<<16);
    u32 o3 = (u32)f2bf(acc[6]) | ((u32)f2bf(acc[7])<<16);
    *(uint4*)(xbar + (size_t)p*FD + f0) = make_uint4(o0,o1,o2,o3);
  }
}

__global__ __launch_bounds__(256) void attn_xbar(const void* __restrict__ xs, const void* __restrict__ xn,
                                                 const float* __restrict__ wa, const int* __restrict__ flag,
                                                 u16* __restrict__ xbar){
  const int lane = threadIdx.x & 63;
  const int p    = blockIdx.x*4 + (threadIdx.x >> 6);
  if (flag[0]) attn_body<true >(xs, xn, wa, xbar, p, lane);
  else         attn_body<false>(xs, xn, wa, xbar, p, lane);
}

// ---------------- Kernel C: out = relu(xbar @ W), MFMA via inline asm (type-proof)
__global__ __launch_bounds__(256) void matvec_out(const u16* __restrict__ xbar,
                                                  const void* __restrict__ w_,
                                                  void* __restrict__ out_,
                                                  const int* __restrict__ flag){
  __shared__ u16 wlds[FD*FD];
  const int tid = threadIdx.x;
  const bool isf32 = (flag[0] != 0);
  if (isf32){
    const float* w = (const float*)w_;
    #pragma unroll
    for(int i=0;i<8;++i){
      const int e = (i*256 + tid)*8;
      float4 A = *(const float4*)(w + e);
      float4 B = *(const float4*)(w + e + 4);
      u32 o0 = (u32)f2bf(A.x) | ((u32)f2bf(A.y)<<16);
      u32 o1 = (u32)f2bf(A.z) | ((u32)f2bf(A.w)<<16);
      u32 o2 = (u32)f2bf(B.x) | ((u32)f2bf(B.y)<<16);
      u32 o3 = (u32)f2bf(B.z) | ((u32)f2bf(B.w)<<16);
      *(uint4*)(wlds + e) = make_uint4(o0,o1,o2,o3);
    }
  } else {
    const u16* w = (const u16*)w_;
    #pragma unroll
    for(int i=0;i<8;++i){
      const int e = (i*256 + tid)*8;
      *(uint4*)(wlds + e) = *(const uint4*)(w + e);
    }
  }
  __syncthreads();

  const int lane = tid & 63, wv = tid >> 6;
  const int col  = lane & 15, quad = lane >> 4;

  // B fragments: B[k = kt*32 + quad*8 + j][n = nt*16 + col]
  i32x4 bfru[8][4];
  #pragma unroll
  for(int nt=0;nt<8;++nt)
    #pragma unroll
    for(int kt=0;kt<4;++kt){
      union { u16 s[8]; i32x4 u; } bb;
      #pragma unroll
      for(int j=0;j<8;++j) bb.s[j] = wlds[(kt*32 + quad*8 + j)*FD + nt*16 + col];
      bfru[nt][kt] = bb.u;
    }

  const int waveG = blockIdx.x*4 + wv;   // 1024 waves
  #pragma unroll
  for(int s=0;s<2;++s){
    const int tile = waveG + s*1024;     // 2048 tiles of 16 rows
    const u16* arow = xbar + (size_t)(tile*16 + col)*FD;
    f32x4 acc[8];
    #pragma unroll
    for(int nt=0;nt<8;++nt){ f32x4 z = {0.f,0.f,0.f,0.f}; acc[nt] = z; }
    #pragma unroll
    for(int kt=0;kt<4;++kt){
      i32x4 av = *(const i32x4*)(arow + kt*32 + quad*8);   // A[m=col][k=kt*32+quad*8+j]
      #pragma unroll
      for(int nt=0;nt<8;++nt){
        // s_nop 1: VALU-write -> MFMA-read SrcA/B hazard; trailing nops: MFMA-write -> VALU-read
        asm volatile("s_nop 1\n\t"
                     "v_mfma_f32_16x16x32_bf16 %0, %1, %2, %0\n\t"
                     "s_nop 7\n\t"
                     "s_nop 7"
                     : "+v"(acc[nt]) : "v"(av), "v"(bfru[nt][kt]));
      }
    }
    if (isf32){
      float* orow = (float*)out_ + (size_t)tile*(16*FD);
      #pragma unroll
      for(int nt=0;nt<8;++nt)
        #pragma unroll
        for(int r=0;r<4;++r)
          orow[(quad*4+r)*FD + nt*16 + col] = fmaxf(acc[nt][r], 0.f);
    } else {
      u16* orow = (u16*)out_ + (size_t)tile*(16*FD);
      #pragma unroll
      for(int nt=0;nt<8;++nt)
        #pragma unroll
        for(int r=0;r<4;++r)
          orow[(quad*4+r)*FD + nt*16 + col] = f2bf(fmaxf(acc[nt][r], 0.f));
    }
  }
}

extern "C" void kernel_launch(void* const* d_in, const int* in_sizes, int n_in,
                              void* d_out, int out_size, void* d_ws, size_t ws_size,
                              hipStream_t stream){
  const void* x_self  = d_in[0];
  const void* x_neigh = d_in[1];
  const void* w_feat  = d_in[2];
  const void* a_self  = d_in[3];
  const void* a_neigh = d_in[4];

  int*   flag = (int*)d_ws;                  // byte 0
  float* wa   = (float*)d_ws + 64;           // byte 256: 256 floats [wa_self | wa_neigh]
  u16*   xbar = (u16*)d_ws + 1024;           // byte 2048: [32768][128] bf16

  prep_wa  <<<FD,      64,  0, stream>>>(w_feat, a_self, a_neigh, (const u16*)x_self, wa, flag);
  attn_xbar<<<NPAIR/4, 256, 0, stream>>>(x_self, x_neigh, wa, flag, xbar);
  matvec_out<<<256,    256, 0, stream>>>(xbar, w_feat, d_out, flag);
}